// Round 2
// baseline (293.023 us; speedup 1.0000x reference)
//
#include <hip/hip_runtime.h>
#include <hip/hip_bf16.h>

// HMLSTMCell2: B=65536, H=128, gates = 513-wide GEMM (K=384) + pointwise epilogue.
// Gate columns 0..511 via bf16 MFMA 16x16x32; column 512 (sz -> hard threshold z_new)
// in fp32/fp64 fused into A staging. Weights pre-converted/swizzled to bf16 in d_ws.

#define MT   32          // rows per block
#define BK   32          // K chunk
#define NKC  12          // 384 / 32
#define COFF 8388608     // c_new offset in d_out (65536*128)
#define ZOFF 16777216    // z_new offset (2*65536*128)

using short8 = __attribute__((ext_vector_type(8))) short;  // 8 bf16 (4 VGPR)
using f32x4  = __attribute__((ext_vector_type(4))) float;  // MFMA acc frag

__device__ __forceinline__ unsigned short f2bf(float f) {
  union { float f; unsigned u; } v; v.f = f;
  unsigned r = (v.u + 0x7FFFu + ((v.u >> 16) & 1u)) >> 16;  // RNE truncate
  return (unsigned short)r;
}

__device__ __forceinline__ void async_copy16(const void* g, void* l) {
  __builtin_amdgcn_global_load_lds(
      (const __attribute__((address_space(1))) unsigned int*)g,
      (__attribute__((address_space(3))) unsigned int*)l, 16, 0, 0);
}

__device__ __forceinline__ float sigm(float x)     { return 1.f / (1.f + __expf(-x)); }
__device__ __forceinline__ float tanh_fast(float x){ return 1.f - 2.f / (1.f + __expf(2.f * x)); }

// d_ws layout: bf16, element ((c*512 + n)*4 + (u ^ (n&3)))*8 + j  holds
// Wc[k = c*32 + u*8 + j][n], where Wc = [W; R; U] (cols 0..511 only).
// The XOR pre-swizzle makes the main kernel's B-frag ds_read_b128 bank-balanced
// while keeping global_load_lds a pure linear copy.
__global__ void prep_weights(const float* __restrict__ W, const float* __restrict__ R,
                             const float* __restrict__ U, unsigned short* __restrict__ Wt) {
  int idx = blockIdx.x * blockDim.x + threadIdx.x;   // 0 .. 24575
  if (idx >= NKC * 512 * 4) return;
  int up = idx & 3;            // physical 16B unit within row
  int n  = (idx >> 2) & 511;   // output column
  int c  = idx >> 11;          // K chunk
  int ul = up ^ (n & 3);       // logical unit
  int k0 = c * 32 + ul * 8;    // global k of first element
  const float* src; int kb;
  if (k0 < 128)      { src = W; kb = 0;   }
  else if (k0 < 256) { src = R; kb = 128; }
  else               { src = U; kb = 256; }
  const float* colp = src + (size_t)(k0 - kb) * 513 + n;
  unsigned short vs[8];
  #pragma unroll
  for (int j = 0; j < 8; ++j) vs[j] = f2bf(colp[j * 513]);
  uint4 o;
  o.x = (unsigned)vs[0] | ((unsigned)vs[1] << 16);
  o.y = (unsigned)vs[2] | ((unsigned)vs[3] << 16);
  o.z = (unsigned)vs[4] | ((unsigned)vs[5] << 16);
  o.w = (unsigned)vs[6] | ((unsigned)vs[7] << 16);
  reinterpret_cast<uint4*>(Wt)[idx] = o;
}

__global__ __launch_bounds__(256)
void hmlstm_main(const float* __restrict__ hb, const float* __restrict__ hs,
                 const float* __restrict__ ht, const float* __restrict__ cs,
                 const float* __restrict__ zp, const float* __restrict__ zbp,
                 const float* __restrict__ W,  const float* __restrict__ R,
                 const float* __restrict__ U,  const float* __restrict__ b,
                 const unsigned short* __restrict__ Wt, float* __restrict__ out)
{
  __shared__ unsigned short ldsW[512 * BK];   // 32 KB, pre-swizzled linear copy
  __shared__ unsigned short ldsA[MT * BK];    // 2 KB, swizzled bf16 A chunk
  __shared__ float ldsWL[384];                // fp32 col-512 weights (for sz)
  __shared__ float ldsSZ[256];                // sz partial reduce

  const int tid  = threadIdx.x;
  const int l    = tid & 63;
  const int wv   = tid >> 6;   // wave 0..3 -> wn
  const int q    = l >> 4;     // quad 0..3
  const int lr   = l & 15;
  const int row0 = blockIdx.x * MT;

  // stage fp32 column-512 weights (sz path) — 384 entries, 256 threads: stride loop
  for (int k = tid; k < 384; k += 256) {
    ldsWL[k] = (k < 128) ? W[k * 513 + 512]
             : (k < 256) ? R[(k - 128) * 513 + 512]
                         : U[(k - 256) * 513 + 512];
  }

  // A-staging assignment: thread -> (row m, 4-float group p); fixed across chunks
  const int m    = tid >> 3;       // 0..31
  const int p    = tid & 7;        // 0..7
  const int arow = row0 + m;
  const float zbv = zbp[arow];
  const float zv  = zp[arow];
  double szacc = 0.0;              // hard-threshold path: keep extra precision

  f32x4 acc[2][8];
  {
    f32x4 zf = {0.f, 0.f, 0.f, 0.f};
    #pragma unroll
    for (int i = 0; i < 2; ++i)
      #pragma unroll
      for (int j = 0; j < 8; ++j) acc[i][j] = zf;
  }

  __syncthreads();  // ldsWL ready

  const int u1  = p >> 1;
  const int sub = (p & 1) * 4;
  const int aWrite = m * BK + ((u1 ^ (m & 3)) * 8) + sub;  // swizzled element idx

  for (int kc = 0; kc < NKC; ++kc) {
    // ---- stage W chunk: async global->LDS, width 16, linear (pre-swizzled) ----
    const unsigned short* gW = Wt + kc * (512 * BK);
    #pragma unroll
    for (int r = 0; r < 8; ++r) {
      int eo = (wv * 8 + r) * 512;                 // 4 waves x 8 rounds x 512 elem
      async_copy16(gW + eo + l * 8, ldsW + eo);    // lane lands at base + lane*16B
    }
    // ---- stage A chunk: fp32 load, scale, sz partial (fp64 acc), bf16 -> LDS ----
    {
      const float* src  = (kc < 4) ? hb : (kc < 8) ? hs : ht;
      const float scale = (kc < 4) ? zbv : (kc < 8) ? 1.f : zv;
      const int col0 = (kc & 3) * 32 + p * 4;
      f32x4 v = *(const f32x4*)(src + (size_t)arow * 128 + col0);
      v *= scale;
      const float* wl = ldsWL + kc * 32 + p * 4;
      szacc += (double)v.x * wl[0] + (double)v.y * wl[1]
             + (double)v.z * wl[2] + (double)v.w * wl[3];
      uint2 pk;
      pk.x = (unsigned)f2bf(v.x) | ((unsigned)f2bf(v.y) << 16);
      pk.y = (unsigned)f2bf(v.z) | ((unsigned)f2bf(v.w) << 16);
      *(uint2*)&ldsA[aWrite] = pk;
    }
    __syncthreads();  // waits vmcnt(0): global_load_lds + A writes complete

    // ---- MFMA: wave tile 32 rows x {4 gates x 32 cols}; K=32 in one step ----
    short8 af[2], bf[8];
    #pragma unroll
    for (int tm = 0; tm < 2; ++tm) {
      int mr = tm * 16 + lr;                       // A[m = lane&15][k = q*8+j]
      af[tm] = *(const short8*)&ldsA[mr * BK + ((q ^ (mr & 3)) * 8)];
    }
    #pragma unroll
    for (int tn = 0; tn < 8; ++tn) {
      int nc = (tn >> 1) * 128 + wv * 32 + (tn & 1) * 16 + lr;  // gate-spread cols
      bf[tn] = *(const short8*)&ldsW[nc * BK + ((q ^ (nc & 3)) * 8)];
    }
    #pragma unroll
    for (int tm = 0; tm < 2; ++tm)
      #pragma unroll
      for (int tn = 0; tn < 8; ++tn)
        acc[tm][tn] = __builtin_amdgcn_mfma_f32_16x16x32_bf16(af[tm], bf[tn], acc[tm][tn], 0, 0, 0);

    __syncthreads();  // protect LDS before next chunk's staging
  }

  // ---- z_new: sz reduce (8 partials per row), hard threshold sz > 0 ----
  ldsSZ[tid] = (float)szacc;
  __syncthreads();
  if (tid < MT) {
    float s = 0.f;
    #pragma unroll
    for (int j = 0; j < 8; ++j) s += ldsSZ[tid * 8 + j];
    s += b[512];
    out[ZOFF + row0 + tid] = (s > 0.f) ? 1.f : 0.f;
  }

  // ---- epilogue: all four gates for (row,col) live in this lane's acc ----
  #pragma unroll
  for (int th = 0; th < 2; ++th) {
    const int col = wv * 32 + th * 16 + lr;
    const float bi = b[col], bg = b[128 + col], bo = b[256 + col], bfv = b[384 + col];
    #pragma unroll
    for (int tm = 0; tm < 2; ++tm) {
      const int rbase = row0 + tm * 16 + q * 4;    // C/D: col=lane&15, row=quad*4+reg
      #pragma unroll
      for (int r = 0; r < 4; ++r) {
        const int row = rbase + r;
        const size_t off = (size_t)row * 128 + col;
        float si = acc[tm][0 + th][r] + bi;
        float sg = acc[tm][2 + th][r] + bg;
        float so = acc[tm][4 + th][r] + bo;
        float sf = acc[tm][6 + th][r] + bfv;
        float iv = sigm(si);
        float gv = tanh_fast(sg);
        float ov = sigm(so);
        float fv = sigm(sf);
        float ig = iv * gv;
        float zr  = zp[row];
        float zbr = zbp[row];
        float cv  = cs[off];
        float hv  = hs[off];
        float cn = (zr == 1.f) ? ig : ((zbr == 0.f) ? cv : cv * fv + ig);
        float hn = (zr == 0.f && zbr == 0.f) ? hv : tanh_fast(cn) * ov;
        out[off]        = hn;
        out[COFF + off] = cn;
      }
    }
  }
}

extern "C" void kernel_launch(void* const* d_in, const int* in_sizes, int n_in,
                              void* d_out, int out_size, void* d_ws, size_t ws_size,
                              hipStream_t stream) {
  const float* hb  = (const float*)d_in[0];
  const float* hs  = (const float*)d_in[1];
  const float* ht  = (const float*)d_in[2];
  const float* cs  = (const float*)d_in[3];
  const float* zp  = (const float*)d_in[4];
  const float* zbp = (const float*)d_in[5];
  const float* W   = (const float*)d_in[6];
  const float* R   = (const float*)d_in[7];
  const float* U   = (const float*)d_in[8];
  const float* b   = (const float*)d_in[9];
  unsigned short* Wt = (unsigned short*)d_ws;   // 12*512*32*2 = 393216 B
  float* out = (float*)d_out;

  prep_weights<<<dim3(96), dim3(256), 0, stream>>>(W, R, U, Wt);
  hmlstm_main<<<dim3(65536 / MT), dim3(256), 0, stream>>>(
      hb, hs, ht, cs, zp, zbp, W, R, U, b, Wt, out);
}

// Round 3
// 251.742 us; speedup vs baseline: 1.1640x; 1.1640x over previous
//
#include <hip/hip_runtime.h>
#include <hip/hip_bf16.h>

// HMLSTMCell2: B=65536, H=128, gates = 513-wide GEMM (K=384) + pointwise epilogue.
// Gate columns 0..511 via bf16 MFMA 16x16x32; column 512 (sz -> hard threshold z_new)
// in fp64 fused into A staging. Weights pre-converted/swizzled to bf16 in d_ws.
// R2->R3: MT 32->128 (512-thr blocks, acc[4][8]) to cut per-dispatch weight
// re-staging traffic 786->196 MB; bank swizzle fixed to ((row>>1)&3).

#define MT   128         // rows per block
#define BK   32          // K chunk
#define NKC  12          // 384 / 32
#define NT   512         // threads per block
#define COFF 8388608     // c_new offset in d_out (65536*128)
#define ZOFF 16777216    // z_new offset (2*65536*128)

using short8 = __attribute__((ext_vector_type(8))) short;  // 8 bf16 (4 VGPR)
using f32x4  = __attribute__((ext_vector_type(4))) float;  // MFMA acc frag

__device__ __forceinline__ unsigned short f2bf(float f) {
  union { float f; unsigned u; } v; v.f = f;
  unsigned r = (v.u + 0x7FFFu + ((v.u >> 16) & 1u)) >> 16;  // RNE truncate
  return (unsigned short)r;
}

__device__ __forceinline__ void async_copy16(const void* g, void* l) {
  __builtin_amdgcn_global_load_lds(
      (const __attribute__((address_space(1))) unsigned int*)g,
      (__attribute__((address_space(3))) unsigned int*)l, 16, 0, 0);
}

__device__ __forceinline__ float sigm(float x)     { return 1.f / (1.f + __expf(-x)); }
__device__ __forceinline__ float tanh_fast(float x){ return 1.f - 2.f / (1.f + __expf(2.f * x)); }

// d_ws layout: bf16, element ((c*512 + n)*4 + (u ^ ((n>>1)&3)))*8 + j holds
// Wc[k = c*32 + u*8 + j][n], Wc = [W; R; U] (cols 0..511). The XOR pre-swizzle
// uses (n>>1)&3 because the bank-relevant low bit of the 64 B row stride is n&1;
// this spreads ds_read_b128 start banks 2/bank (free per m136).
__global__ void prep_weights(const float* __restrict__ W, const float* __restrict__ R,
                             const float* __restrict__ U, unsigned short* __restrict__ Wt) {
  int idx = blockIdx.x * blockDim.x + threadIdx.x;   // 0 .. 24575
  if (idx >= NKC * 512 * 4) return;
  int up = idx & 3;            // physical 16B unit within row
  int n  = (idx >> 2) & 511;   // output column
  int c  = idx >> 11;          // K chunk
  int ul = up ^ ((n >> 1) & 3);// logical unit
  int k0 = c * 32 + ul * 8;    // global k of first element
  const float* src; int kb;
  if (k0 < 128)      { src = W; kb = 0;   }
  else if (k0 < 256) { src = R; kb = 128; }
  else               { src = U; kb = 256; }
  const float* colp = src + (size_t)(k0 - kb) * 513 + n;
  unsigned short vs[8];
  #pragma unroll
  for (int j = 0; j < 8; ++j) vs[j] = f2bf(colp[j * 513]);
  uint4 o;
  o.x = (unsigned)vs[0] | ((unsigned)vs[1] << 16);
  o.y = (unsigned)vs[2] | ((unsigned)vs[3] << 16);
  o.z = (unsigned)vs[4] | ((unsigned)vs[5] << 16);
  o.w = (unsigned)vs[6] | ((unsigned)vs[7] << 16);
  reinterpret_cast<uint4*>(Wt)[idx] = o;
}

__global__ __launch_bounds__(512, 2)
void hmlstm_main(const float* __restrict__ hb, const float* __restrict__ hs,
                 const float* __restrict__ ht, const float* __restrict__ cs,
                 const float* __restrict__ zp, const float* __restrict__ zbp,
                 const float* __restrict__ W,  const float* __restrict__ R,
                 const float* __restrict__ U,  const float* __restrict__ b,
                 const unsigned short* __restrict__ Wt, float* __restrict__ out)
{
  __shared__ unsigned short ldsW[512 * BK];      // 32 KB, pre-swizzled linear copy
  __shared__ unsigned short ldsA[2][MT * BK];    // 16 KB, double-buffered A chunks
  __shared__ float  ldsWL[384];                  // fp32 col-512 weights (for sz)
  __shared__ double ldsSZ[NT];                   // sz partial reduce (fp64)

  const int tid  = threadIdx.x;
  const int l    = tid & 63;
  const int wv   = tid >> 6;   // 0..7
  const int ws   = wv & 3;     // col slice
  const int wr   = wv >> 2;    // row half
  const int q    = l >> 4;     // quad 0..3
  const int lr   = l & 15;
  const int row0 = blockIdx.x * MT;

  // stage fp32 column-512 weights (sz path)
  for (int k = tid; k < 384; k += NT) {
    ldsWL[k] = (k < 128) ? W[k * 513 + 512]
             : (k < 256) ? R[(k - 128) * 513 + 512]
                         : U[(k - 256) * 513 + 512];
  }

  // A-staging assignment: thread -> (row m, 8-float group p); fixed across chunks
  const int m    = tid >> 2;       // 0..127
  const int p    = tid & 3;        // 0..3
  const int arow = row0 + m;
  const float zbv = zbp[arow];
  const float zv  = zp[arow];
  double szacc = 0.0;

  f32x4 acc[4][8];
  {
    f32x4 zf = {0.f, 0.f, 0.f, 0.f};
    #pragma unroll
    for (int i = 0; i < 4; ++i)
      #pragma unroll
      for (int j = 0; j < 8; ++j) acc[i][j] = zf;
  }

  // swizzled 16B write slot for A staging
  const int aW = m * BK + ((p ^ ((m >> 1) & 3)) * 8);

  __syncthreads();  // ldsWL ready before first stageA

  // stage A chunk kc into buffer buf (fp32 load, scale, fp64 sz partial, bf16 pack)
  auto stageA = [&](int kc, int buf) {
    const float* src  = (kc < 4) ? hb : (kc < 8) ? hs : ht;
    const float scale = (kc < 4) ? zbv : (kc < 8) ? 1.f : zv;
    const float* sp = src + (size_t)arow * 128 + (kc & 3) * 32 + p * 8;
    f32x4 v0 = *(const f32x4*)sp;
    f32x4 v1 = *(const f32x4*)(sp + 4);
    v0 *= scale; v1 *= scale;
    const float* wl = ldsWL + kc * 32 + p * 8;
    szacc += (double)v0.x * wl[0] + (double)v0.y * wl[1]
           + (double)v0.z * wl[2] + (double)v0.w * wl[3]
           + (double)v1.x * wl[4] + (double)v1.y * wl[5]
           + (double)v1.z * wl[6] + (double)v1.w * wl[7];
    uint4 pk;
    pk.x = (unsigned)f2bf(v0.x) | ((unsigned)f2bf(v0.y) << 16);
    pk.y = (unsigned)f2bf(v0.z) | ((unsigned)f2bf(v0.w) << 16);
    pk.z = (unsigned)f2bf(v1.x) | ((unsigned)f2bf(v1.y) << 16);
    pk.w = (unsigned)f2bf(v1.z) | ((unsigned)f2bf(v1.w) << 16);
    *(uint4*)&ldsA[buf][aW] = pk;
  };

  stageA(0, 0);

  for (int kc = 0; kc < NKC; ++kc) {
    const int cur = kc & 1, nxt = cur ^ 1;
    // ---- stage W chunk kc: async global->LDS, width 16, linear (pre-swizzled) ----
    const unsigned short* gW = Wt + kc * (512 * BK);
    #pragma unroll
    for (int r = 0; r < 4; ++r) {
      int eo = (wv * 4 + r) * 512;                 // 8 waves x 4 rounds x 512 elem
      async_copy16(gW + eo + l * 8, ldsW + eo);    // lane lands at base + lane*16B
    }
    // ---- stage next A chunk into the other buffer (overlaps W-stage drain) ----
    if (kc < NKC - 1) stageA(kc + 1, nxt);
    __syncthreads();  // drains W global_load_lds + A global loads/ds_writes

    // ---- MFMA: wave tile 64 rows x {4 gates x 32 cols}; K=32 per iter ----
    short8 bfr[8];
    #pragma unroll
    for (int tn = 0; tn < 8; ++tn) {
      int nc = (tn >> 1) * 128 + ws * 32 + (tn & 1) * 16 + lr;  // gate-spread cols
      bfr[tn] = *(const short8*)&ldsW[nc * BK + ((q ^ ((nc >> 1) & 3)) * 8)];
    }
    #pragma unroll
    for (int s = 0; s < 4; ++s) {
      int mr = wr * 64 + s * 16 + lr;              // A[m = lane&15][k = q*8+j]
      short8 af = *(const short8*)&ldsA[cur][mr * BK + ((q ^ ((mr >> 1) & 3)) * 8)];
      #pragma unroll
      for (int tn = 0; tn < 8; ++tn)
        acc[s][tn] = __builtin_amdgcn_mfma_f32_16x16x32_bf16(af, bfr[tn], acc[s][tn], 0, 0, 0);
    }
    __syncthreads();  // protect ldsW/ldsA before next chunk's staging
  }

  // ---- z_new: fp64 sz reduce (4 partials per row), hard threshold sz > 0 ----
  ldsSZ[tid] = szacc;
  __syncthreads();
  if (tid < MT) {
    double ss = ldsSZ[tid * 4] + ldsSZ[tid * 4 + 1] + ldsSZ[tid * 4 + 2] + ldsSZ[tid * 4 + 3];
    float s = (float)ss + b[512];
    out[ZOFF + row0 + tid] = (s > 0.f) ? 1.f : 0.f;
  }

  // ---- epilogue: all four gates for (row,col) live in this lane's acc ----
  float bias[2][4];
  #pragma unroll
  for (int th = 0; th < 2; ++th) {
    const int col = ws * 32 + th * 16 + lr;
    bias[th][0] = b[col];       bias[th][1] = b[128 + col];
    bias[th][2] = b[256 + col]; bias[th][3] = b[384 + col];
  }
  #pragma unroll
  for (int s = 0; s < 4; ++s) {
    #pragma unroll
    for (int r = 0; r < 4; ++r) {
      const int row = row0 + wr * 64 + s * 16 + q * 4 + r;  // C/D: row=quad*4+reg
      const float zr  = zp[row];
      const float zbr = zbp[row];
      const size_t rowoff = (size_t)row * 128;
      #pragma unroll
      for (int th = 0; th < 2; ++th) {
        const int col = ws * 32 + th * 16 + lr;             // C/D: col=lane&15
        const size_t off = rowoff + col;
        float si = acc[s][0 + th][r] + bias[th][0];
        float sg = acc[s][2 + th][r] + bias[th][1];
        float so = acc[s][4 + th][r] + bias[th][2];
        float sf = acc[s][6 + th][r] + bias[th][3];
        float iv = sigm(si);
        float gv = tanh_fast(sg);
        float ov = sigm(so);
        float fv = sigm(sf);
        float ig = iv * gv;
        float cv = cs[off];
        float hv = hs[off];
        float cn = (zr == 1.f) ? ig : ((zbr == 0.f) ? cv : cv * fv + ig);
        float hn = (zr == 0.f && zbr == 0.f) ? hv : tanh_fast(cn) * ov;
        out[off]        = hn;
        out[COFF + off] = cn;
      }
    }
  }
}

extern "C" void kernel_launch(void* const* d_in, const int* in_sizes, int n_in,
                              void* d_out, int out_size, void* d_ws, size_t ws_size,
                              hipStream_t stream) {
  const float* hb  = (const float*)d_in[0];
  const float* hs  = (const float*)d_in[1];
  const float* ht  = (const float*)d_in[2];
  const float* cs  = (const float*)d_in[3];
  const float* zp  = (const float*)d_in[4];
  const float* zbp = (const float*)d_in[5];
  const float* W   = (const float*)d_in[6];
  const float* R   = (const float*)d_in[7];
  const float* U   = (const float*)d_in[8];
  const float* b   = (const float*)d_in[9];
  unsigned short* Wt = (unsigned short*)d_ws;   // 12*512*32*2 = 393216 B
  float* out = (float*)d_out;

  prep_weights<<<dim3(96), dim3(256), 0, stream>>>(W, R, U, Wt);
  hmlstm_main<<<dim3(65536 / MT), dim3(NT), 0, stream>>>(
      hb, hs, ht, cs, zp, zbp, W, R, U, b, Wt, out);
}